// Round 11
// baseline (383.017 us; speedup 1.0000x reference)
//
#include <hip/hip_runtime.h>
#include <cstdint>

// ShortTermLSTM on MI355X: batched LSTM, transposed-GEMM f16 MFMA, activations
// in exp2 domain (raw v_exp_f32), packed-f32 pair activation.
// Plateau ledger: R15 251 / R16 269 / R17 262 / R18 256 / R21 250 / R22 258 /
// R23 274. Falsified: topology, ILP schedule, VALU count, LDS traffic,
// wave-occupancy, x-latency, setprio, 3-domain residency (3 reg-diet fails;
// R21's genuine 38% occ was wall-flat). Conclusion: the 128 serial per-step
// __syncthreads rendezvous are the invariant cost (~250us for every >=2
// domain config).
// R24 (this): ZERO-BARRIER design. One WAVE owns the whole recurrence for 16
// seqs (all 25 tiles). h hand-off is wave-internal through a single s_h
// buffer: LDS DS ops of one wave execute in order, so one lgkmcnt fence per
// step (threadfence_block) replaces the barrier. 768 single-wave blocks
// (launch_bounds(64,1)); no inter-wave coupling at all.
//   W: pairs 0..9 all-kc in regs (80 frags = 320 regs); pairs 10,11 + tile24
//   in LDS s_W (20 frags, 20,480 B, read per step). Total regs ~410 <= 450
//   no-spill zone (m08). LDS/block 24,832 B -> 3 blocks/CU co-resident.
//   Each lane also does its own x-refresh (seq=m, feat=quad, 3 ds_write_b16).
// Pair-tile layout (tile<24): tileA rows {i(u0),i(u1),f(u0),f(u1)} x4 quads,
// tileB {g,g,o,o}; u0 = 8*pair + 2*quad, u1 = u0+1. acc A=(i0,i1,f0,f1),
// B=(g0,g1,o0,o1) -> v_pk_*_f32 activation; ds_write_b32 h per pair.
// k-map identity for h (k=u); x/bias k100..113.
// Residual error: dropped h*W_hh_lo (~6e-5/step); measured margin ~4x.

#define H_UNITS 100
#define T_STEPS 128
#define S_BLK   16
#define NSEQ    12288
#define NBLK    (NSEQ / S_BLK)   // 768 single-wave blocks
#define NTILE   25
#define KSTR    136              // s_h row stride (ushorts)
#define LOG2E   1.4426950408889634f
#define TWO_L   2.8853900817779268f   // 2*log2(e)

typedef __attribute__((ext_vector_type(8))) _Float16 halfx8;
typedef __attribute__((ext_vector_type(8))) unsigned short ushortx8;
typedef __attribute__((ext_vector_type(4))) float floatx4;
typedef __attribute__((ext_vector_type(2))) float floatx2;

__device__ __forceinline__ unsigned short f32_to_f16u(float x) {
    _Float16 h = (_Float16)x;                       // v_cvt_f16_f32 (RNE)
    return __builtin_bit_cast(unsigned short, h);
}
__device__ __forceinline__ float f16u_to_f32(unsigned short u) {
    _Float16 h = __builtin_bit_cast(_Float16, u);
    return (float)h;
}
#if __has_builtin(__builtin_amdgcn_exp2f)
__device__ __forceinline__ float fexp2(float x) { return __builtin_amdgcn_exp2f(x); }
#else
__device__ __forceinline__ float fexp2(float x) { return exp2f(x); }
#endif

// ---------------------------------------------------------------------------
// Prep: pack W (pre-scaled into exp2 domain) into MFMA A-operand fragments.
// Pair-tile row map (tile<24): pr=tile>>1, half=tile&1, reg=m&3, qr=m>>2:
//   gate = (reg>>1) + 2*half   (A: i,f ; B: g,o)
//   unit = 8*pr + 2*qr + (reg&1)
//   n = gate*100 + unit        (torch gate order i,f,g,o)
// Tile 24: n = (m&3)*100 + 96 + (m>>2)  (i,f,g,o-per-quad layout).
// k-map: identity for h (k<100); x/bias cols:
//   k100..103 x_hi(W_hi); k104..107 x_lo(W_hi); k108..111 x_hi(W_lo);
//   k112/113 bias hi/lo (A=1.0); k114..127 zero.
// ---------------------------------------------------------------------------
__global__ void lstm_prep_pack(const float* __restrict__ W_ih,
                               const float* __restrict__ W_hh,
                               const float* __restrict__ b_ih,
                               const float* __restrict__ b_hh,
                               ushortx8* __restrict__ Bpack) {
    int t = blockIdx.x * 256 + threadIdx.x;   // (tile,kc,lane): 25*4*64 = 6400
    if (t >= NTILE * 4 * 64) return;
    int lane = t & 63;
    int kc   = (t >> 6) & 3;
    int tile = t >> 8;
    int m    = lane & 15;
    int n;
    if (tile < 24) {
        int pr = tile >> 1, half = tile & 1;
        int reg = m & 3,   qr   = m >> 2;
        int g = (reg >> 1) + 2 * half;
        int u = 8 * pr + 2 * qr + (reg & 1);
        n = g * 100 + u;
    } else {
        n = (m & 3) * 100 + 96 + (m >> 2);
    }
    float sc = (n >= 200 && n < 300) ? (2.0f * LOG2E) : LOG2E;   // g rows get 2x
    int k0 = kc * 32 + ((lane >> 4) & 3) * 8;
    ushortx8 v;
#pragma unroll
    for (int j = 0; j < 8; ++j) {
        int k = k0 + j;
        unsigned short w = 0;
        if (k < 100) {
            w = f32_to_f16u(W_hh[n * 100 + k] * sc);             // identity k-map
        } else if (k < 108) {
            w = f32_to_f16u(W_ih[n * 4 + ((k - 100) & 3)] * sc); // hi W (x_hi & x_lo)
        } else if (k < 112) {
            float wf = W_ih[n * 4 + (k - 108)] * sc;             // lo W (x_hi)
            unsigned short hi = f32_to_f16u(wf);
            w = f32_to_f16u(wf - f16u_to_f32(hi));
        } else if (k == 112) {
            float bb = (b_ih[n] + b_hh[n]) * sc;                 // b_hi (A=1.0)
            w = f32_to_f16u(bb);
        } else if (k == 113) {
            float bb = (b_ih[n] + b_hh[n]) * sc;                 // b_lo (A=1.0)
            unsigned short hi = f32_to_f16u(bb);
            w = f32_to_f16u(bb - f16u_to_f32(hi));
        }
        v[j] = w;
    }
    Bpack[t] = v;
}

// ---------------------------------------------------------------------------
// Main: ONE WAVE = 16 sequences, all 25 tiles, full T loop, no barriers.
// Lane (m = lane&15 -> seq, quad = lane>>4): per pair p computes units
// 8p+2q, 8p+2q+1; tile24 unit 96+q. Lane also refreshes x feature c=quad.
// Step: fence(lgkmcnt) -> read hh[0..3] -> compiler fence -> 12 pairs +
// tile24 (MFMA + packed activation, h writes to s_h) -> x(t+1) writes.
// Wave-internal in-order DS ordering replaces __syncthreads.
// ---------------------------------------------------------------------------
__global__ void __launch_bounds__(64, 1)
lstm_main(const float* __restrict__ x, const ushortx8* __restrict__ Bpack,
          float* __restrict__ out) {
    __shared__ __align__(16) unsigned short s_h[16 * KSTR];   // 4,352 B (single buf)
    __shared__ __align__(16) ushortx8       s_W[20 * 64];     // 20,480 B

    const int lane = threadIdx.x & 63;
    const int m    = lane & 15;
    const int quad = lane >> 4;
    const int q2   = quad << 1;
    const int seq0 = blockIdx.x * S_BLK;

    // ---- W pairs 0..9 (tiles 0..19), all kc -> regs (80 frags = 320 regs)
    halfx8 wfA[10][4], wfB[10][4];
#pragma unroll
    for (int p = 0; p < 10; ++p)
#pragma unroll
        for (int kc = 0; kc < 4; ++kc) {
            wfA[p][kc] = __builtin_bit_cast(halfx8, Bpack[((2 * p) * 4 + kc) * 64 + lane]);
            wfB[p][kc] = __builtin_bit_cast(halfx8, Bpack[((2 * p + 1) * 4 + kc) * 64 + lane]);
        }
    // ---- LDS W: tiles 20..23 (f = (tile-20)*4+kc) + tile24 (f = 16+kc)
    for (int i = lane; i < 20 * 64; i += 64) {
        int f = i >> 6, ln = i & 63;
        int tile = (f < 16) ? (20 + (f >> 2)) : 24;
        int kc   = (f < 16) ? (f & 3) : (f - 16);
        s_W[i] = Bpack[(tile * 4 + kc) * 64 + ln];
    }

    // ---- zero s_h (h(0)=0; k114..127 stay 0)
    for (int i = lane; i < (16 * KSTR) / 2; i += 64)
        ((unsigned int*)s_h)[i] = 0u;

    // ---- x(0) + bias init. Lane handles seq=m, feature c=quad (all 64 lanes).
    const float* xb = x + (size_t)(seq0 + m) * (T_STEPS * 4) + quad;
    {
        float x0 = xb[0];
        unsigned short hi = f32_to_f16u(x0);
        __syncthreads();   // single wave: drains staging/zero writes
        s_h[m * KSTR + 100 + quad] = hi;                          // x_hi (W_hi)
        s_h[m * KSTR + 108 + quad] = hi;                          // x_hi (W_lo)
        s_h[m * KSTR + 104 + quad] = f32_to_f16u(x0 - f16u_to_f32(hi)); // x_lo
        if (lane < 32)
            s_h[(lane >> 1) * KSTR + 112 + (lane & 1)] = 0x3C00;  // bias sel = 1.0
    }

    floatx2 cpr[12];   // cell state per pair (2*log2e domain)
#pragma unroll
    for (int p = 0; p < 12; ++p) cpr[p] = (floatx2){0.0f, 0.0f};
    float c24 = 0.0f;

    const int rowOff = m * KSTR;
    const int aOff   = rowOff + quad * 8;

    for (int t = 0; t < T_STEPS; ++t) {
        // prefetch x(t+1) early (consumed ~full step later)
        int tn = t + 1; if (tn > T_STEPS - 1) tn = T_STEPS - 1;
        float xn = xb[tn * 4];

        __threadfence_block();   // lgkmcnt(0): prior step's h/x writes done

        halfx8 hh[4];
#pragma unroll
        for (int kc = 0; kc < 4; ++kc)
            hh[kc] = *(const halfx8*)(s_h + aOff + kc * 32);   // ds_read_b128

        asm volatile("" ::: "memory");   // pin hh reads above this step's writes

        const bool last = (t == T_STEPS - 1);

        auto gemm4 = [&](halfx8 w0, halfx8 w1, halfx8 w2, halfx8 w3) {
            floatx4 a = {0.0f, 0.0f, 0.0f, 0.0f};
            a = __builtin_amdgcn_mfma_f32_16x16x32_f16(w0, hh[0], a, 0, 0, 0);
            a = __builtin_amdgcn_mfma_f32_16x16x32_f16(w1, hh[1], a, 0, 0, 0);
            a = __builtin_amdgcn_mfma_f32_16x16x32_f16(w2, hh[2], a, 0, 0, 0);
            a = __builtin_amdgcn_mfma_f32_16x16x32_f16(w3, hh[3], a, 0, 0, 0);
            return a;
        };

        // packed 2-cell activation: accA=(i0,i1,f0,f1), accB=(g0,g1,o0,o1)
        auto activatePair = [&](floatx4 aA, floatx4 aB, floatx2& cm, int p) {
            floatx2 ei = {fexp2(aA[0]), fexp2(aA[1])};   // e^i
            floatx2 ef = {fexp2(aA[2]), fexp2(aA[3])};   // e^f
            floatx2 eg = {fexp2(aB[0]), fexp2(aB[1])};   // e^{2g}
            floatx2 eo = {fexp2(aB[2]), fexp2(aB[3])};   // e^o
            floatx2 a  = ei + 1.0f;                      // v_pk_add_f32
            floatx2 b  = ef + 1.0f;
            floatx2 d  = eg + 1.0f;
            floatx2 p1 = eo + 1.0f;
            floatx2 e2s = eg * TWO_L - TWO_L;            // v_pk_fma_f32
            floatx2 q  = a * d;
            floatx2 qb = q * b;
            floatx2 r  = {__builtin_amdgcn_rcpf(qb[0]), __builtin_amdgcn_rcpf(qb[1])};
            floatx2 eib = ei * b;
            floatx2 efq = ef * q;
            floatx2 tt  = eib * e2s;
            floatx2 nm  = efq * cm + tt;                 // v_pk_fma_f32
            floatx2 c2  = nm * r;
            cm = c2;
            floatx2 cc = {fminf(c2[0], 115.0f), fminf(c2[1], 115.0f)};
            floatx2 ec = {fexp2(cc[0]), fexp2(cc[1])};   // e^{2c}
            floatx2 p2 = ec + 1.0f;
            floatx2 nu = ec - 1.0f;
            floatx2 pp = p1 * p2;
            floatx2 r2 = {__builtin_amdgcn_rcpf(pp[0]), __builtin_amdgcn_rcpf(pp[1])};
            floatx2 eon = eo * nu;
            floatx2 hv  = eon * r2;
            if (!last) {
                unsigned int pk = (unsigned int)f32_to_f16u(hv[0]) |
                                  ((unsigned int)f32_to_f16u(hv[1]) << 16);
                *(unsigned int*)&s_h[rowOff + 8 * p + q2] = pk;   // ds_write_b32
            } else {
                *(floatx2*)&out[(size_t)(seq0 + m) * H_UNITS + 8 * p + q2] = hv;
            }
        };

        // ---- pairs 0..9: W fully in registers
#pragma unroll
        for (int p = 0; p < 10; ++p) {
            floatx4 aA = gemm4(wfA[p][0], wfA[p][1], wfA[p][2], wfA[p][3]);
            floatx4 aB = gemm4(wfB[p][0], wfB[p][1], wfB[p][2], wfB[p][3]);
            activatePair(aA, aB, cpr[p], p);
        }
        // ---- pairs 10,11: W from LDS (tiles 20..23)
#pragma unroll
        for (int p = 10; p < 12; ++p) {
            int fb = (p - 10) * 8;   // 8 frags per pair
            halfx8 wa0 = __builtin_bit_cast(halfx8, s_W[(fb + 0) * 64 + lane]);
            halfx8 wa1 = __builtin_bit_cast(halfx8, s_W[(fb + 1) * 64 + lane]);
            halfx8 wa2 = __builtin_bit_cast(halfx8, s_W[(fb + 2) * 64 + lane]);
            halfx8 wa3 = __builtin_bit_cast(halfx8, s_W[(fb + 3) * 64 + lane]);
            floatx4 aA = gemm4(wa0, wa1, wa2, wa3);
            halfx8 wb0 = __builtin_bit_cast(halfx8, s_W[(fb + 4) * 64 + lane]);
            halfx8 wb1 = __builtin_bit_cast(halfx8, s_W[(fb + 5) * 64 + lane]);
            halfx8 wb2 = __builtin_bit_cast(halfx8, s_W[(fb + 6) * 64 + lane]);
            halfx8 wb3 = __builtin_bit_cast(halfx8, s_W[(fb + 7) * 64 + lane]);
            floatx4 aB = gemm4(wb0, wb1, wb2, wb3);
            activatePair(aA, aB, cpr[p], p);
        }
        // ---- tile 24 (units 96..99): W from LDS, scalar activation
        {
            halfx8 w0 = __builtin_bit_cast(halfx8, s_W[(16 + 0) * 64 + lane]);
            halfx8 w1 = __builtin_bit_cast(halfx8, s_W[(16 + 1) * 64 + lane]);
            halfx8 w2 = __builtin_bit_cast(halfx8, s_W[(16 + 2) * 64 + lane]);
            halfx8 w3 = __builtin_bit_cast(halfx8, s_W[(16 + 3) * 64 + lane]);
            floatx4 acc = gemm4(w0, w1, w2, w3);
            float ei = fexp2(acc[0]);
            float ef = fexp2(acc[1]);
            float eg = fexp2(acc[2]);
            float eo = fexp2(acc[3]);
            float a  = 1.0f + ei, b = 1.0f + ef;
            float d  = eg + 1.0f;
            float e2s = fmaf(eg, TWO_L, -TWO_L);
            float q  = a * d;
            float r  = __builtin_amdgcn_rcpf(q * b);
            float nm = fmaf(ef * q, c24, (ei * b) * e2s);
            float c2 = nm * r;
            c24 = c2;
            float cc = fminf(c2, 115.0f);
            float ec = fexp2(cc);
            float r2 = __builtin_amdgcn_rcpf((1.0f + eo) * (ec + 1.0f));
            float h  = (eo * (ec - 1.0f)) * r2;
            if (!last) {
                s_h[rowOff + 96 + quad] = f32_to_f16u(h);          // k = unit
            } else {
                out[(size_t)(seq0 + m) * H_UNITS + 96 + quad] = h;
            }
        }

        if (!last) {   // x(t+1): lane refreshes feature c=quad of seq m
            unsigned short hi = f32_to_f16u(xn);
            s_h[rowOff + 100 + quad] = hi;
            s_h[rowOff + 108 + quad] = hi;
            s_h[rowOff + 104 + quad] = f32_to_f16u(xn - f16u_to_f32(hi));
        }
        // no barrier: wave-internal in-order DS + next-iteration fence
    }
}

extern "C" void kernel_launch(void* const* d_in, const int* in_sizes, int n_in,
                              void* d_out, int out_size, void* d_ws, size_t ws_size,
                              hipStream_t stream) {
    const float* x    = (const float*)d_in[0];   // [4096,3,128,4]
    const float* W_ih = (const float*)d_in[1];   // [400,4]
    const float* W_hh = (const float*)d_in[2];   // [400,100]
    const float* b_ih = (const float*)d_in[3];   // [400]
    const float* b_hh = (const float*)d_in[4];   // [400]
    ushortx8* Bpack = (ushortx8*)d_ws;           // 25*4*64*16 B = 102,400 B

    lstm_prep_pack<<<25, 256, 0, stream>>>(W_ih, W_hh, b_ih, b_hh, Bpack);
    lstm_main<<<NBLK, 64, 0, stream>>>(x, Bpack, (float*)d_out);
}

// Round 12
// 282.030 us; speedup vs baseline: 1.3581x; 1.3581x over previous
//
#include <hip/hip_runtime.h>
#include <cstdint>

// ShortTermLSTM on MI355X: batched LSTM, transposed-GEMM f16 MFMA, cell fully
// in registers, fused-rcp activations in the exp2 domain (raw v_exp_f32).
// FINAL RESTORE of best-measured kernel (R21: dispatch 249.8us, bench 284.4).
// Session ledger: R15 251 / R16 269 / R17 262 / R18 256 / R19 256 / R20 280 /
// R21 249.8 / R22 258 / R23 274 / R24 350 (zero-barrier, single-wave issue
// serialization). Falsified levers: topology, ILP schedule, VALU count, LDS
// traffic, reg-granule occupancy (3x), 3-domain residency, x-load latency,
// setprio, barrier elimination. Structural constraint: per-step all-to-all h
// dependency forces 128 serial block-wide rendezvous; trans-op floor
// (7 exp-rcp/cell, 175 wave-ops/step/block) + rendezvous spread ~= 3100
// cyc/step wall. Every >=2-barrier-domain config lands 250-260us.
// Geometry: 768 blocks x 512 thr x 16 seqs; wave w owns pair w (tiles
// 2w,2w+1, all kc in 32 AGPR); waves 0-3 + pair 8+w from s_W; wave 4 tile24;
// waves 5,6 x-refresh; wave 7 light. One barrier/step. LDS 45,568 B.
// Pair-tile layout (tile<24): tileA rows {i(u0),i(u1),f(u0),f(u1)} x4 quads,
// tileB {g,g,o,o}; u0 = 8*pair + 2*quad, u1 = u0+1. Lane acc:
// accA=(i0,i1,f0,f1), accB=(g0,g1,o0,o1) -> v_pk_*_f32 activation; one
// ds_write_b32 per pair. k-map identity for h (k=u); x/bias k100..113.
// Residual error: dropped h*W_hh_lo (~6e-5/step); measured margin ~4x.

#define H_UNITS 100
#define T_STEPS 128
#define S_BLK   16
#define NSEQ    12288
#define NBLK    (NSEQ / S_BLK)   // 768
#define NTILE   25               // 100 units / 4 rows-of-4 per tile
#define KSTR    136              // LDS h row stride (ushorts)
#define LOG2E   1.4426950408889634f
#define TWO_L   2.8853900817779268f   // 2*log2(e)

typedef __attribute__((ext_vector_type(8))) _Float16 halfx8;
typedef __attribute__((ext_vector_type(8))) unsigned short ushortx8;
typedef __attribute__((ext_vector_type(4))) float floatx4;
typedef __attribute__((ext_vector_type(2))) float floatx2;

__device__ __forceinline__ unsigned short f32_to_f16u(float x) {
    _Float16 h = (_Float16)x;                       // v_cvt_f16_f32 (RNE)
    return __builtin_bit_cast(unsigned short, h);
}
__device__ __forceinline__ float f16u_to_f32(unsigned short u) {
    _Float16 h = __builtin_bit_cast(_Float16, u);
    return (float)h;
}
#if __has_builtin(__builtin_amdgcn_exp2f)
__device__ __forceinline__ float fexp2(float x) { return __builtin_amdgcn_exp2f(x); }
#else
__device__ __forceinline__ float fexp2(float x) { return exp2f(x); }
#endif

// ---------------------------------------------------------------------------
// Prep: pack W (pre-scaled into exp2 domain) into MFMA A-operand fragments.
// Pair-tile row map (tile<24): pr=tile>>1, half=tile&1, reg=m&3, qr=m>>2:
//   gate = (reg>>1) + 2*half   (A: i,f ; B: g,o)
//   unit = 8*pr + 2*qr + (reg&1)
//   n = gate*100 + unit        (torch gate order i,f,g,o)
// Tile 24: n = (m&3)*100 + 96 + (m>>2)  (i,f,g,o-per-quad layout).
// k-map: identity for h (k<100); x/bias cols:
//   k100..103 x_hi(W_hi); k104..107 x_lo(W_hi); k108..111 x_hi(W_lo);
//   k112/113 bias hi/lo (A=1.0); k114..127 zero.
// ---------------------------------------------------------------------------
__global__ void lstm_prep_pack(const float* __restrict__ W_ih,
                               const float* __restrict__ W_hh,
                               const float* __restrict__ b_ih,
                               const float* __restrict__ b_hh,
                               ushortx8* __restrict__ Bpack) {
    int t = blockIdx.x * 256 + threadIdx.x;   // (tile,kc,lane): 25*4*64 = 6400
    if (t >= NTILE * 4 * 64) return;
    int lane = t & 63;
    int kc   = (t >> 6) & 3;
    int tile = t >> 8;
    int m    = lane & 15;
    int n;
    if (tile < 24) {
        int pr = tile >> 1, half = tile & 1;
        int reg = m & 3,   qr   = m >> 2;
        int g = (reg >> 1) + 2 * half;
        int u = 8 * pr + 2 * qr + (reg & 1);
        n = g * 100 + u;
    } else {
        n = (m & 3) * 100 + 96 + (m >> 2);
    }
    float sc = (n >= 200 && n < 300) ? (2.0f * LOG2E) : LOG2E;   // g rows get 2x
    int k0 = kc * 32 + ((lane >> 4) & 3) * 8;
    ushortx8 v;
#pragma unroll
    for (int j = 0; j < 8; ++j) {
        int k = k0 + j;
        unsigned short w = 0;
        if (k < 100) {
            w = f32_to_f16u(W_hh[n * 100 + k] * sc);             // identity k-map
        } else if (k < 108) {
            w = f32_to_f16u(W_ih[n * 4 + ((k - 100) & 3)] * sc); // hi W (x_hi & x_lo)
        } else if (k < 112) {
            float wf = W_ih[n * 4 + (k - 108)] * sc;             // lo W (x_hi)
            unsigned short hi = f32_to_f16u(wf);
            w = f32_to_f16u(wf - f16u_to_f32(hi));
        } else if (k == 112) {
            float bb = (b_ih[n] + b_hh[n]) * sc;                 // b_hi (A=1.0)
            w = f32_to_f16u(bb);
        } else if (k == 113) {
            float bb = (b_ih[n] + b_hh[n]) * sc;                 // b_lo (A=1.0)
            unsigned short hi = f32_to_f16u(bb);
            w = f32_to_f16u(bb - f16u_to_f32(hi));
        }
        v[j] = w;
    }
    Bpack[t] = v;
}

// ---------------------------------------------------------------------------
// Main: one block = 16 sequences, 8 waves, full T loop.
// Wave w: own pair p0=w (tiles 2w,2w+1, all kc in regs).
//   w<4 : second pair p1=8+w (tiles 16+2w,17+2w) with W from s_W.
//   w==4: tile 24 (units 96..99) with W from s_W.
//   w in {5,6}: x-refresh threads (tids 320..447).
// s_W frag f: f<32 -> tile 16+(f>>2), kc=f&3 ; f in 32..35 -> tile24 kc=f-32.
// One barrier per step.
// ---------------------------------------------------------------------------
__global__ void __launch_bounds__(512, 4)
lstm_main(const float* __restrict__ x, const ushortx8* __restrict__ Bpack,
          float* __restrict__ out) {
    __shared__ __align__(16) unsigned short s_A[2][16 * KSTR];   // ping-pong, 8,704 B
    __shared__ __align__(16) ushortx8       s_W[36 * 64];        // 36,864 B

    const int tid  = threadIdx.x;
    const int lane = tid & 63;
    const int wavu = __builtin_amdgcn_readfirstlane(tid >> 6);   // 0..7
    const int seq0 = blockIdx.x * S_BLK;
    const int m    = lane & 15;
    const int quad = lane >> 4;
    const int q2   = quad << 1;

    // ---- own-pair W fragments, all kc in regs (8 frags = 32 regs)
    halfx8 wfA[4], wfB[4];
#pragma unroll
    for (int kc = 0; kc < 4; ++kc) {
        wfA[kc] = __builtin_bit_cast(halfx8, Bpack[((2 * wavu) * 4 + kc) * 64 + lane]);
        wfB[kc] = __builtin_bit_cast(halfx8, Bpack[((2 * wavu + 1) * 4 + kc) * 64 + lane]);
    }

    // ---- LDS weight staging: tiles 16..23 (all kc) + tile 24 (all kc)
    for (int i = tid; i < 36 * 64; i += 512) {
        int f = i >> 6, ln = i & 63;
        int tile = (f < 32) ? (16 + (f >> 2)) : 24;
        int kc   = (f < 32) ? (f & 3) : (f - 32);
        s_W[i] = Bpack[(tile * 4 + kc) * 64 + ln];
    }

    // refresh-thread x pointer (valid for tid in [320,448)): 16 seqs x 8 cols
    const int rt   = tid - 320;
    const bool refr = (rt >= 0) && (rt < 128);
    const int rtc  = refr ? rt : 0;
    const int rs   = rtc & 15, rc = (rtc >> 4) & 7;
    const float* xb = x + (size_t)(seq0 + rs) * (T_STEPS * 4) + (rc & 3);

    // ---- zero both buffers (h(0)=0; k114..127 stay 0 forever)
    for (int i = tid; i < (2 * 16 * KSTR) / 2; i += 512)
        ((unsigned int*)s_A)[i] = 0u;
    float x0 = 0.0f;
    if (refr) x0 = xb[0];
    __syncthreads();
    // ---- x(t=0) into buf0; constant bias-select cols into BOTH buffers
    if (refr) {
        unsigned short hi = f32_to_f16u(x0);
        if (rc < 4) {
            s_A[0][rs * KSTR + 100 + rc] = hi;                    // x_hi (W_hi)
            s_A[0][rs * KSTR + 108 + rc] = hi;                    // x_hi (W_lo)
        } else {
            s_A[0][rs * KSTR + 104 + (rc - 4)] =
                f32_to_f16u(x0 - f16u_to_f32(hi));                // x_lo (W_hi)
        }
    } else if (tid < 64) {
        // 64 writes: 2 bufs x 16 rows x 2 bias cols (k112,k113) = 1.0
        int b = tid >> 5, r = (tid >> 1) & 15, col = 112 + (tid & 1);
        s_A[b][r * KSTR + col] = 0x3C00;
    }
    __syncthreads();   // init + s_W visible before first read

    floatx2 c0 = {0.0f, 0.0f};    // own pair cell state (2*log2e domain)
    floatx2 c1 = {0.0f, 0.0f};    // second pair (waves 0..3)
    float   c24 = 0.0f;           // tile 24 (wave 4)

    const int rowOff = m * KSTR;
    const int aOff   = rowOff + quad * 8;
    const int hb     = wavu * 512 + lane;    // s_W heavy-pair base (A at +0, B at +256)

    for (int t = 0; t < T_STEPS; ++t) {
        const int bR = t & 1;
        const unsigned short* base  = s_A[bR];
        unsigned short*       baseW = s_A[bR ^ 1];

        // prefetch x(t+1) — issued before compute phase to hide latency
        float xnext = 0.0f;
        if (refr) {
            int tn = t + 1; if (tn > T_STEPS - 1) tn = T_STEPS - 1;
            xnext = xb[tn * 4];
        }

        halfx8 hh[4];
#pragma unroll
        for (int kc = 0; kc < 4; ++kc)
            hh[kc] = *(const halfx8*)(base + aOff + kc * 32);   // ds_read_b128

        const bool last = (t == T_STEPS - 1);

        auto gemm4 = [&](halfx8 w0, halfx8 w1, halfx8 w2, halfx8 w3) {
            floatx4 a = {0.0f, 0.0f, 0.0f, 0.0f};
            a = __builtin_amdgcn_mfma_f32_16x16x32_f16(w0, hh[0], a, 0, 0, 0);
            a = __builtin_amdgcn_mfma_f32_16x16x32_f16(w1, hh[1], a, 0, 0, 0);
            a = __builtin_amdgcn_mfma_f32_16x16x32_f16(w2, hh[2], a, 0, 0, 0);
            a = __builtin_amdgcn_mfma_f32_16x16x32_f16(w3, hh[3], a, 0, 0, 0);
            return a;
        };

        // packed 2-cell activation: accA=(i0,i1,f0,f1), accB=(g0,g1,o0,o1)
        auto activatePair = [&](floatx4 aA, floatx4 aB, floatx2& cm, int p) {
            floatx2 ei = {fexp2(aA[0]), fexp2(aA[1])};   // e^i
            floatx2 ef = {fexp2(aA[2]), fexp2(aA[3])};   // e^f
            floatx2 eg = {fexp2(aB[0]), fexp2(aB[1])};   // e^{2g}
            floatx2 eo = {fexp2(aB[2]), fexp2(aB[3])};   // e^o
            floatx2 a  = ei + 1.0f;                      // v_pk_add_f32
            floatx2 b  = ef + 1.0f;
            floatx2 d  = eg + 1.0f;
            floatx2 p1 = eo + 1.0f;
            floatx2 e2s = eg * TWO_L - TWO_L;            // v_pk_fma_f32
            floatx2 q  = a * d;
            floatx2 qb = q * b;
            floatx2 r  = {__builtin_amdgcn_rcpf(qb[0]), __builtin_amdgcn_rcpf(qb[1])};
            floatx2 eib = ei * b;
            floatx2 efq = ef * q;
            floatx2 tt  = eib * e2s;
            floatx2 nm  = efq * cm + tt;                 // v_pk_fma_f32
            floatx2 c2  = nm * r;
            cm = c2;
            floatx2 cc = {fminf(c2[0], 115.0f), fminf(c2[1], 115.0f)};
            floatx2 ec = {fexp2(cc[0]), fexp2(cc[1])};   // e^{2c}
            floatx2 p2 = ec + 1.0f;
            floatx2 nu = ec - 1.0f;
            floatx2 pp = p1 * p2;
            floatx2 r2 = {__builtin_amdgcn_rcpf(pp[0]), __builtin_amdgcn_rcpf(pp[1])};
            floatx2 eon = eo * nu;
            floatx2 hv  = eon * r2;
            if (!last) {
                unsigned int pk = (unsigned int)f32_to_f16u(hv[0]) |
                                  ((unsigned int)f32_to_f16u(hv[1]) << 16);
                *(unsigned int*)&baseW[rowOff + 8 * p + q2] = pk;   // ds_write_b32
            } else {
                *(floatx2*)&out[(size_t)(seq0 + m) * H_UNITS + 8 * p + q2] = hv;
            }
        };

        // ---- own pair (W in regs)
        {
            floatx4 aA = gemm4(wfA[0], wfA[1], wfA[2], wfA[3]);
            floatx4 aB = gemm4(wfB[0], wfB[1], wfB[2], wfB[3]);
            activatePair(aA, aB, c0, wavu);
        }

        if (wavu < 4) {
            // ---- second pair p1 = 8+wavu (tiles 16+2w / 17+2w), W from LDS
            halfx8 wa0 = __builtin_bit_cast(halfx8, s_W[hb + 0 * 64]);
            halfx8 wa1 = __builtin_bit_cast(halfx8, s_W[hb + 1 * 64]);
            halfx8 wa2 = __builtin_bit_cast(halfx8, s_W[hb + 2 * 64]);
            halfx8 wa3 = __builtin_bit_cast(halfx8, s_W[hb + 3 * 64]);
            floatx4 aA = gemm4(wa0, wa1, wa2, wa3);
            halfx8 wb0 = __builtin_bit_cast(halfx8, s_W[hb + 256 + 0 * 64]);
            halfx8 wb1 = __builtin_bit_cast(halfx8, s_W[hb + 256 + 1 * 64]);
            halfx8 wb2 = __builtin_bit_cast(halfx8, s_W[hb + 256 + 2 * 64]);
            halfx8 wb3 = __builtin_bit_cast(halfx8, s_W[hb + 256 + 3 * 64]);
            floatx4 aB = gemm4(wb0, wb1, wb2, wb3);
            activatePair(aA, aB, c1, 8 + wavu);
        } else if (wavu == 4) {
            // ---- tile 24 (units 96..99), W from LDS, scalar activation
            halfx8 w0 = __builtin_bit_cast(halfx8, s_W[2048 + 0 * 64 + lane]);
            halfx8 w1 = __builtin_bit_cast(halfx8, s_W[2048 + 1 * 64 + lane]);
            halfx8 w2 = __builtin_bit_cast(halfx8, s_W[2048 + 2 * 64 + lane]);
            halfx8 w3 = __builtin_bit_cast(halfx8, s_W[2048 + 3 * 64 + lane]);
            floatx4 acc = gemm4(w0, w1, w2, w3);
            float ei = fexp2(acc[0]);
            float ef = fexp2(acc[1]);
            float eg = fexp2(acc[2]);
            float eo = fexp2(acc[3]);
            float a  = 1.0f + ei, b = 1.0f + ef;
            float d  = eg + 1.0f;
            float e2s = fmaf(eg, TWO_L, -TWO_L);
            float q  = a * d;
            float r  = __builtin_amdgcn_rcpf(q * b);
            float nm = fmaf(ef * q, c24, (ei * b) * e2s);
            float c2 = nm * r;
            c24 = c2;
            float cc = fminf(c2, 115.0f);
            float ec = fexp2(cc);
            float r2 = __builtin_amdgcn_rcpf((1.0f + eo) * (ec + 1.0f));
            float h  = (eo * (ec - 1.0f)) * r2;
            if (!last) {
                baseW[rowOff + 96 + quad] = f32_to_f16u(h);        // k = unit
            } else {
                out[(size_t)(seq0 + m) * H_UNITS + 96 + quad] = h;
            }
        }

        if (refr && !last) {                     // x(t+1) -> other buffer
            unsigned short hi = f32_to_f16u(xnext);
            if (rc < 4) {
                baseW[rs * KSTR + 100 + rc] = hi;
                baseW[rs * KSTR + 108 + rc] = hi;
            } else {
                baseW[rs * KSTR + 104 + (rc - 4)] =
                    f32_to_f16u(xnext - f16u_to_f32(hi));
            }
        }
        __syncthreads();   // single barrier/step: covers both cross-step hazards
    }
}

extern "C" void kernel_launch(void* const* d_in, const int* in_sizes, int n_in,
                              void* d_out, int out_size, void* d_ws, size_t ws_size,
                              hipStream_t stream) {
    const float* x    = (const float*)d_in[0];   // [4096,3,128,4]
    const float* W_ih = (const float*)d_in[1];   // [400,4]
    const float* W_hh = (const float*)d_in[2];   // [400,100]
    const float* b_ih = (const float*)d_in[3];   // [400]
    const float* b_hh = (const float*)d_in[4];   // [400]
    ushortx8* Bpack = (ushortx8*)d_ws;           // 25*4*64*16 B = 102,400 B

    lstm_prep_pack<<<25, 256, 0, stream>>>(W_ih, W_hh, b_ih, b_hh, Bpack);
    lstm_main<<<NBLK, 512, 0, stream>>>(x, Bpack, (float*)d_out);
}